// Round 1
// baseline (703.511 us; speedup 1.0000x reference)
//
#include <hip/hip_runtime.h>
#include <cstdint>
#include <cstddef>

#define B_   4
#define T_   2048
#define D_   1024
#define NTOK (B_*T_)          // 8192 tokens
#define HID  4096             // MLP_HIDDEN
#define PDIM (6*D_)           // 6144

typedef int v4i __attribute__((ext_vector_type(4)));

__device__ __forceinline__ float sigf(float x){ return 1.0f/(1.0f+expf(-x)); }

// ---------- block reductions (256 threads) ----------
__device__ __forceinline__ float bsum256(float v, float* sm, int tid){
#pragma unroll
  for (int o=32;o;o>>=1) v += __shfl_down(v,o);
  if ((tid&63)==0) sm[tid>>6]=v;
  __syncthreads();
  float r = sm[0]+sm[1]+sm[2]+sm[3];
  __syncthreads();
  return r;
}
__device__ __forceinline__ void bsummax256(float& s, float& m, float* sm, int tid){
#pragma unroll
  for (int o=32;o;o>>=1){ s += __shfl_down(s,o); m = fmaxf(m,__shfl_down(m,o)); }
  if ((tid&63)==0){ sm[tid>>6]=s; sm[4+(tid>>6)]=m; }
  __syncthreads();
  s = sm[0]+sm[1]+sm[2]+sm[3];
  m = fmaxf(fmaxf(sm[4],sm[5]),fmaxf(sm[6],sm[7]));
  __syncthreads();
}

__device__ __forceinline__ uint32_t pack4(float a, float b, float c, float d, float k){
  int q0=(int)rintf(a*k); q0 = q0<-128?-128:(q0>127?127:q0);
  int q1=(int)rintf(b*k); q1 = q1<-128?-128:(q1>127?127:q1);
  int q2=(int)rintf(c*k); q2 = q2<-128?-128:(q2>127?127:q2);
  int q3=(int)rintf(d*k); q3 = q3<-128?-128:(q3>127?127:q3);
  return (uint32_t)(q0&255) | ((uint32_t)(q1&255)<<8) | ((uint32_t)(q2&255)<<16) | ((uint32_t)(q3&255)<<24);
}

// ---------- weight ternarization ----------
struct WMeta {
  const float* w[6];
  int8_t* q[6];
  int n[6];
};

__global__ __launch_bounds__(256) void k_wabs(WMeta meta, float* __restrict__ partial){
  int mat = blockIdx.y;
  const float* w = meta.w[mat];
  int n = meta.n[mat];
  int tid = threadIdx.x;
  float s = 0.f;
  for (int i = blockIdx.x*256 + tid; i < n; i += 256*gridDim.x) s += fabsf(w[i]);
  __shared__ float sm[4];
#pragma unroll
  for (int o=32;o;o>>=1) s += __shfl_down(s,o);
  if ((tid&63)==0) sm[tid>>6]=s;
  __syncthreads();
  if (tid==0) partial[mat*256 + blockIdx.x] = sm[0]+sm[1]+sm[2]+sm[3];
}

__global__ __launch_bounds__(256) void k_wfin(WMeta meta, const float* __restrict__ partial, float* __restrict__ wdeq){
  int mat = blockIdx.x;
  int tid = threadIdx.x;
  float s = partial[mat*256 + tid];
  __shared__ float sm[4];
#pragma unroll
  for (int o=32;o;o>>=1) s += __shfl_down(s,o);
  if ((tid&63)==0) sm[tid>>6]=s;
  __syncthreads();
  if (tid==0){
    float mean = (sm[0]+sm[1]+sm[2]+sm[3]) / (float)meta.n[mat];
    wdeq[mat] = fmaxf(mean, 1e-5f);   // = 1/ws (dequant scale)
  }
}

__global__ __launch_bounds__(256) void k_wquant(WMeta meta, const float* __restrict__ wdeq){
  int mat = blockIdx.y;
  const float* w = meta.w[mat];
  int8_t* q = meta.q[mat];
  int n = meta.n[mat];
  float ws = 1.0f / wdeq[mat];
  for (int i = blockIdx.x*256 + threadIdx.x; i < n; i += 256*gridDim.x){
    int v = (int)rintf(w[i]*ws);
    v = v < -1 ? -1 : (v > 1 ? 1 : v);
    q[i] = (int8_t)v;
  }
}

// ---------- adaLN: params = silu(c) @ adaln_w.T + adaln_b ----------
__global__ __launch_bounds__(256) void k_adaln(const float* __restrict__ c, const float* __restrict__ w,
                                               const float* __restrict__ bias, float* __restrict__ params){
  int wv = threadIdx.x>>6, lane = threadIdx.x&63;
  int oidx = blockIdx.x*4 + wv;           // 0..24575
  int b = oidx / PDIM, j = oidx % PDIM;
  const float* cr = c + b*D_;
  const float* wr = w + (size_t)j*D_;
  float s = 0.f;
  for (int k = lane; k < D_; k += 64){
    float cv = cr[k];
    s += (cv*sigf(cv)) * wr[k];
  }
#pragma unroll
  for (int o=32;o;o>>=1) s += __shfl_down(s,o);
  if (lane==0) params[oidx] = s + bias[j];
}

// ---------- [residual +] LayerNorm + modulate + rmsnorm + int8 quant (one token/block) ----------
template<int RES>
__global__ __launch_bounds__(256) void k_lnmodq(const float* __restrict__ xin,
    const float* __restrict__ addv, const float* __restrict__ params,
    int shift_off, int scale_off, int gate_off,
    float* __restrict__ x2out, int8_t* __restrict__ xq, float* __restrict__ dq){
  int tok = blockIdx.x;
  int b = tok >> 11;
  int tid = threadIdx.x;
  __shared__ float sm[8];
  const float* pb = params + (size_t)b*PDIM;
  float4 v = ((const float4*)(xin + (size_t)tok*D_))[tid];
  if (RES){
    float4 a = ((const float4*)(addv + (size_t)tok*D_))[tid];
    float4 g = ((const float4*)(pb + gate_off))[tid];
    v.x = fmaf(g.x,a.x,v.x); v.y = fmaf(g.y,a.y,v.y);
    v.z = fmaf(g.z,a.z,v.z); v.w = fmaf(g.w,a.w,v.w);
    ((float4*)(x2out + (size_t)tok*D_))[tid] = v;
  }
  float mu = bsum256(v.x+v.y+v.z+v.w, sm, tid) * (1.0f/D_);
  float t0=v.x-mu, t1=v.y-mu, t2=v.z-mu, t3=v.w-mu;
  float var = bsum256(t0*t0+t1*t1+t2*t2+t3*t3, sm, tid) * (1.0f/D_);
  float rstd = rsqrtf(var + 1e-6f);
  float4 sc = ((const float4*)(pb + scale_off))[tid];
  float4 sh = ((const float4*)(pb + shift_off))[tid];
  float y0 = fmaf(t0*rstd, 1.0f+sc.x, sh.x);
  float y1 = fmaf(t1*rstd, 1.0f+sc.y, sh.y);
  float y2 = fmaf(t2*rstd, 1.0f+sc.z, sh.z);
  float y3 = fmaf(t3*rstd, 1.0f+sc.w, sh.w);
  float ssq = y0*y0+y1*y1+y2*y2+y3*y3;
  float mx = fmaxf(fmaxf(fabsf(y0),fabsf(y1)),fmaxf(fabsf(y2),fabsf(y3)));
  bsummax256(ssq, mx, sm, tid);
  float rms = rsqrtf(ssq*(1.0f/D_) + 1e-8f);
  float a = fmaxf(mx*rms, 1e-5f);
  float s = 127.0f/a;
  float k = rms*s;
  ((uint32_t*)(xq + (size_t)tok*D_))[tid] = pack4(y0,y1,y2,y3,k);
  if (tid==0) dq[tok] = 1.0f/s;
}

// ---------- i8 GEMM: Out[M,N] = (Aq[M,K] . Bq[N,K]^T) * adq[row] * wdq ----------
// FINAL=1 fuses: Out = resid + gate_mlp * val   (down-proj epilogue)
template<int FINAL>
__global__ __launch_bounds__(256) void k_gemm(const int8_t* __restrict__ Aq, const int8_t* __restrict__ Bq,
    float* __restrict__ Out, const float* __restrict__ adq, const float* __restrict__ wdq_ptr,
    int N, int K, const float* __restrict__ resid, const float* __restrict__ params){
  __shared__ int8_t lA[8192], lB[8192];
  const int tid = threadIdx.x;
  const int wave = tid>>6, lane = tid&63;
  const int row0 = blockIdx.y<<7, col0 = blockIdx.x<<7;
  const int wm = (wave>>1)<<6, wn = (wave&1)<<6;
  v4i acc[4][4];
#pragma unroll
  for (int m=0;m<4;m++)
#pragma unroll
    for (int n=0;n<4;n++) acc[m][n] = (v4i){0,0,0,0};
  const int rA = lane&15, kg = lane>>4;
  for (int k0=0;k0<K;k0+=64){
#pragma unroll
    for (int p=0;p<2;p++){
      int idx = p*256 + tid;
      int r = idx>>2, cb = (idx&3)<<4;
      const int8_t* ga = Aq + (size_t)(row0+r)*K + k0 + cb;
      const int8_t* gb = Bq + (size_t)(col0+r)*K + k0 + cb;
      __builtin_amdgcn_global_load_lds((const __attribute__((address_space(1))) void*)ga,
        (__attribute__((address_space(3))) void*)(lA + p*4096 + wave*1024), 16, 0, 0);
      __builtin_amdgcn_global_load_lds((const __attribute__((address_space(1))) void*)gb,
        (__attribute__((address_space(3))) void*)(lB + p*4096 + wave*1024), 16, 0, 0);
    }
    __syncthreads();
    const v4i* la4 = (const v4i*)lA;
    const v4i* lb4 = (const v4i*)lB;
    v4i af[4], bf[4];
#pragma unroll
    for (int m=0;m<4;m++) af[m] = la4[((wm + m*16 + rA)<<2) + kg];
#pragma unroll
    for (int n=0;n<4;n++) bf[n] = lb4[((wn + n*16 + rA)<<2) + kg];
#pragma unroll
    for (int m=0;m<4;m++)
#pragma unroll
      for (int n=0;n<4;n++)
        acc[m][n] = __builtin_amdgcn_mfma_i32_16x16x64_i8(af[m], bf[n], acc[m][n], 0, 0, 0);
    __syncthreads();
  }
  float wdq = wdq_ptr[0];
  int rr = (lane>>4)<<2, cl = lane&15;
#pragma unroll
  for (int m=0;m<4;m++){
#pragma unroll
    for (int r=0;r<4;r++){
      int row = row0 + wm + m*16 + rr + r;
      float scale = adq[row]*wdq;
#pragma unroll
      for (int n=0;n<4;n++){
        int col = col0 + wn + n*16 + cl;
        size_t oi = (size_t)row*N + col;
        float val = (float)acc[m][n][r]*scale;
        if (FINAL){
          int bb = row>>11;
          val = resid[oi] + params[(size_t)bb*PDIM + 5*D_ + col]*val;
        }
        Out[oi] = val;
      }
    }
  }
}

// ---------- fused gate-proj GEMM: computes both halves of the 8192-wide output,
// writes silu(gate)*y  [M,4096] ----------
__global__ __launch_bounds__(256) void k_gemm_gate(const int8_t* __restrict__ Aq, const int8_t* __restrict__ Wg,
    float* __restrict__ Out, const float* __restrict__ adq, const float* __restrict__ wdq_ptr, int K){
  __shared__ int8_t lA[8192], lBg[8192], lBy[8192];
  const int tid = threadIdx.x;
  const int wave = tid>>6, lane = tid&63;
  const int row0 = blockIdx.y<<7, col0 = blockIdx.x<<7;
  const int wm = (wave>>1)<<6, wn = (wave&1)<<6;
  v4i accg[4][4], accy[4][4];
#pragma unroll
  for (int m=0;m<4;m++)
#pragma unroll
    for (int n=0;n<4;n++){ accg[m][n] = (v4i){0,0,0,0}; accy[m][n] = (v4i){0,0,0,0}; }
  const int rA = lane&15, kg = lane>>4;
  for (int k0=0;k0<K;k0+=64){
#pragma unroll
    for (int p=0;p<2;p++){
      int idx = p*256 + tid;
      int r = idx>>2, cb = (idx&3)<<4;
      const int8_t* ga  = Aq + (size_t)(row0+r)*K + k0 + cb;
      const int8_t* gbg = Wg + (size_t)(col0+r)*K + k0 + cb;
      const int8_t* gby = Wg + (size_t)(HID + col0+r)*K + k0 + cb;
      __builtin_amdgcn_global_load_lds((const __attribute__((address_space(1))) void*)ga,
        (__attribute__((address_space(3))) void*)(lA  + p*4096 + wave*1024), 16, 0, 0);
      __builtin_amdgcn_global_load_lds((const __attribute__((address_space(1))) void*)gbg,
        (__attribute__((address_space(3))) void*)(lBg + p*4096 + wave*1024), 16, 0, 0);
      __builtin_amdgcn_global_load_lds((const __attribute__((address_space(1))) void*)gby,
        (__attribute__((address_space(3))) void*)(lBy + p*4096 + wave*1024), 16, 0, 0);
    }
    __syncthreads();
    const v4i* la4 = (const v4i*)lA;
    const v4i* lg4 = (const v4i*)lBg;
    const v4i* ly4 = (const v4i*)lBy;
    v4i af[4], bg[4], by[4];
#pragma unroll
    for (int m=0;m<4;m++) af[m] = la4[((wm + m*16 + rA)<<2) + kg];
#pragma unroll
    for (int n=0;n<4;n++){ bg[n] = lg4[((wn + n*16 + rA)<<2) + kg]; by[n] = ly4[((wn + n*16 + rA)<<2) + kg]; }
#pragma unroll
    for (int m=0;m<4;m++)
#pragma unroll
      for (int n=0;n<4;n++){
        accg[m][n] = __builtin_amdgcn_mfma_i32_16x16x64_i8(af[m], bg[n], accg[m][n], 0, 0, 0);
        accy[m][n] = __builtin_amdgcn_mfma_i32_16x16x64_i8(af[m], by[n], accy[m][n], 0, 0, 0);
      }
    __syncthreads();
  }
  float wdq = wdq_ptr[0];
  int rr = (lane>>4)<<2, cl = lane&15;
#pragma unroll
  for (int m=0;m<4;m++){
#pragma unroll
    for (int r=0;r<4;r++){
      int row = row0 + wm + m*16 + rr + r;
      float scale = adq[row]*wdq;
#pragma unroll
      for (int n=0;n<4;n++){
        int col = col0 + wn + n*16 + cl;
        float gv = (float)accg[m][n][r]*scale;
        float yv = (float)accy[m][n][r]*scale;
        Out[(size_t)row*HID + col] = gv*sigf(gv)*yv;
      }
    }
  }
}

// ---------- i' = silu(i)*(1-sigmoid(f));  f' = sigmoid(f) ----------
__global__ __launch_bounds__(256) void k_ewif(float* __restrict__ ibuf, float* __restrict__ fbuf, int n4){
  for (int k = blockIdx.x*256 + threadIdx.x; k < n4; k += gridDim.x*256){
    float4 iv = ((float4*)ibuf)[k];
    float4 fv = ((float4*)fbuf)[k];
    float f0=sigf(fv.x), f1=sigf(fv.y), f2=sigf(fv.z), f3=sigf(fv.w);
    float4 io, fo;
    io.x = iv.x*sigf(iv.x)*(1.0f-f0);
    io.y = iv.y*sigf(iv.y)*(1.0f-f1);
    io.z = iv.z*sigf(iv.z)*(1.0f-f2);
    io.w = iv.w*sigf(iv.w)*(1.0f-f3);
    fo.x=f0; fo.y=f1; fo.z=f2; fo.w=f3;
    ((float4*)ibuf)[k] = io;
    ((float4*)fbuf)[k] = fo;
  }
}

// ---------- chunked linear-recurrence scan: h_t = f_t*h_{t-1} + i_t ----------
// 4096 channels (b,d), T=2048, 32 chunks x 64 steps
__global__ __launch_bounds__(256) void k_scanA(const float* __restrict__ f, const float* __restrict__ ii,
                                               float* __restrict__ Ac, float* __restrict__ Hc){
  int idx = blockIdx.x*256 + threadIdx.x;   // < 131072
  int ch = idx >> 12;
  int c  = idx & 4095;
  int b = c >> 10, d = c & 1023;
  size_t base = ((size_t)(b*T_ + ch*64))*D_ + d;
  float a = 1.f, h = 0.f;
  for (int t=0;t<64;t++){
    float ft = f[base + (size_t)t*D_];
    float it = ii[base + (size_t)t*D_];
    a *= ft;
    h = ft*h + it;
  }
  Ac[ch*4096 + c] = a;
  Hc[ch*4096 + c] = h;
}
__global__ __launch_bounds__(256) void k_scanB(const float* __restrict__ Ac, const float* __restrict__ Hc,
                                               float* __restrict__ H0){
  int c = blockIdx.x*256 + threadIdx.x;     // 4096
  float h = 0.f;
  for (int ch=0; ch<32; ch++){
    H0[ch*4096 + c] = h;
    h = Ac[ch*4096 + c]*h + Hc[ch*4096 + c];
  }
}
__global__ __launch_bounds__(256) void k_scanC(const float* __restrict__ f, const float* __restrict__ ii,
                                               const float* __restrict__ H0, float* __restrict__ hout){
  int idx = blockIdx.x*256 + threadIdx.x;
  int ch = idx >> 12;
  int c  = idx & 4095;
  int b = c >> 10, d = c & 1023;
  size_t base = ((size_t)(b*T_ + ch*64))*D_ + d;
  float h = H0[ch*4096 + c];
  for (int t=0;t<64;t++){
    float ft = f[base + (size_t)t*D_];
    float it = ii[base + (size_t)t*D_];
    h = ft*h + it;
    hout[base + (size_t)t*D_] = h;
  }
}

// ---------- o = rmsnorm_head(h)*gnorm_w*(g*sig(g)); then row rmsnorm + quant ----------
__global__ __launch_bounds__(256) void k_ogateq(const float* __restrict__ h, const float* __restrict__ g,
    const float* __restrict__ gnw, int8_t* __restrict__ xq, float* __restrict__ dq){
  int tok = blockIdx.x, tid = threadIdx.x;
  __shared__ float sm[8];
  float4 hv = ((const float4*)(h + (size_t)tok*D_))[tid];
  float ss = hv.x*hv.x + hv.y*hv.y + hv.z*hv.z + hv.w*hv.w;
  ss += __shfl_xor(ss,1); ss += __shfl_xor(ss,2); ss += __shfl_xor(ss,4); ss += __shfl_xor(ss,8);
  float rh = rsqrtf(ss*(1.0f/64.0f) + 1e-5f);
  float4 gv = ((const float4*)(g + (size_t)tok*D_))[tid];
  int hd = (tid*4)&63;
  float o0 = hv.x*rh*gnw[hd+0]*(gv.x*sigf(gv.x));
  float o1 = hv.y*rh*gnw[hd+1]*(gv.y*sigf(gv.y));
  float o2 = hv.z*rh*gnw[hd+2]*(gv.z*sigf(gv.z));
  float o3 = hv.w*rh*gnw[hd+3]*(gv.w*sigf(gv.w));
  float ssq = o0*o0+o1*o1+o2*o2+o3*o3;
  float mx = fmaxf(fmaxf(fabsf(o0),fabsf(o1)),fmaxf(fabsf(o2),fabsf(o3)));
  bsummax256(ssq, mx, sm, tid);
  float rms = rsqrtf(ssq*(1.0f/D_) + 1e-8f);
  float a = fmaxf(mx*rms, 1e-5f);
  float s = 127.0f/a;
  float k = rms*s;
  ((uint32_t*)(xq + (size_t)tok*D_))[tid] = pack4(o0,o1,o2,o3,k);
  if (tid==0) dq[tok] = 1.0f/s;
}

// ---------- quantize swiglu output (4096-wide rows) ----------
__global__ __launch_bounds__(256) void k_mlpq(const float* __restrict__ hsw, int8_t* __restrict__ xq,
                                              float* __restrict__ dq){
  int tok = blockIdx.x, tid = threadIdx.x;
  __shared__ float sm[8];
  const float4* r4 = (const float4*)(hsw + (size_t)tok*HID);
  float4 v[4];
  float ssq = 0.f, mx = 0.f;
#pragma unroll
  for (int j=0;j<4;j++){
    v[j] = r4[tid + j*256];
    ssq += v[j].x*v[j].x + v[j].y*v[j].y + v[j].z*v[j].z + v[j].w*v[j].w;
    mx = fmaxf(mx, fmaxf(fmaxf(fabsf(v[j].x),fabsf(v[j].y)),fmaxf(fabsf(v[j].z),fabsf(v[j].w))));
  }
  bsummax256(ssq, mx, sm, tid);
  float rms = rsqrtf(ssq*(1.0f/HID) + 1e-8f);
  float a = fmaxf(mx*rms, 1e-5f);
  float s = 127.0f/a;
  float k = rms*s;
#pragma unroll
  for (int j=0;j<4;j++)
    ((uint32_t*)(xq + (size_t)tok*HID))[tid + j*256] = pack4(v[j].x,v[j].y,v[j].z,v[j].w,k);
  if (tid==0) dq[tok] = 1.0f/s;
}

// =====================================================================

extern "C" void kernel_launch(void* const* d_in, const int* in_sizes, int n_in,
                              void* d_out, int out_size, void* d_ws, size_t ws_size,
                              hipStream_t stream){
  (void)in_sizes; (void)n_in; (void)out_size; (void)ws_size;
  const float* x     = (const float*)d_in[0];
  const float* c     = (const float*)d_in[1];
  const float* aw    = (const float*)d_in[2];
  const float* ab    = (const float*)d_in[3];
  const float* wi    = (const float*)d_in[4];
  const float* wf    = (const float*)d_in[5];
  const float* wg    = (const float*)d_in[6];
  const float* gnw   = (const float*)d_in[7];
  const float* wo    = (const float*)d_in[8];
  const float* wgate = (const float*)d_in[9];
  const float* wdown = (const float*)d_in[10];
  float* out = (float*)d_out;

  char* ws = (char*)d_ws;
  size_t off = 0;
  auto alloc = [&](size_t b){ size_t r = off; off += (b + 255) & ~(size_t)255; return r; };

  size_t oWQ[6];
  oWQ[0] = alloc(1024*1024);            // wi q
  oWQ[1] = alloc(1024*1024);            // wf q
  oWQ[2] = alloc(1024*1024);            // wg q
  oWQ[3] = alloc(1024*1024);            // wo q
  oWQ[4] = alloc((size_t)8192*1024);    // gate q
  oWQ[5] = alloc((size_t)1024*4096);    // down q
  size_t oWDEQ = alloc(6*4);
  size_t oPART = alloc(6*256*4);
  size_t oPAR  = alloc((size_t)4*PDIM*4);
  size_t oS1 = alloc(NTOK*4), oS2 = alloc(NTOK*4), oS3 = alloc(NTOK*4), oSH = alloc(NTOK*4);
  size_t oXQA  = alloc((size_t)NTOK*D_);                 // 8MB int8 (reused 3x)
  size_t oPOOL = alloc((size_t)5*NTOK*D_*4);             // 160MB: I|F|G|H|AT; hsw overlays [0,128MB), xqh overlays AT
  size_t oX2   = alloc((size_t)NTOK*D_*4);
  size_t oSA = alloc((size_t)32*4096*4), oSHc = alloc((size_t)32*4096*4), oSH0 = alloc((size_t)32*4096*4);

  float*  params = (float*)(ws+oPAR);
  float*  wdeq   = (float*)(ws+oWDEQ);
  float*  part   = (float*)(ws+oPART);
  float*  s1 = (float*)(ws+oS1); float* s2 = (float*)(ws+oS2);
  float*  s3 = (float*)(ws+oS3); float* sh = (float*)(ws+oSH);
  int8_t* xqa = (int8_t*)(ws+oXQA);
  float*  bufI  = (float*)(ws+oPOOL);
  float*  bufF  = bufI + (size_t)NTOK*D_;
  float*  bufG  = bufF + (size_t)NTOK*D_;
  float*  bufH  = bufG + (size_t)NTOK*D_;
  float*  bufAT = bufH + (size_t)NTOK*D_;
  float*  hsw   = bufI;                                        // [NTOK][4096] f32, overlays I..H
  int8_t* xqh   = (int8_t*)bufAT;                              // [NTOK][4096] i8, overlays AT
  float*  x2    = (float*)(ws+oX2);
  float*  scAc = (float*)(ws+oSA); float* scHc = (float*)(ws+oSHc); float* scH0 = (float*)(ws+oSH0);

  WMeta meta;
  meta.w[0]=wi; meta.w[1]=wf; meta.w[2]=wg; meta.w[3]=wo; meta.w[4]=wgate; meta.w[5]=wdown;
  for (int m=0;m<6;m++) meta.q[m] = (int8_t*)(ws+oWQ[m]);
  meta.n[0]=meta.n[1]=meta.n[2]=meta.n[3]=1024*1024; meta.n[4]=8192*1024; meta.n[5]=1024*4096;

  // --- weight ternarization ---
  k_wabs  <<<dim3(256,6), 256, 0, stream>>>(meta, part);
  k_wfin  <<<6,           256, 0, stream>>>(meta, part, wdeq);
  k_wquant<<<dim3(2048,6),256, 0, stream>>>(meta, wdeq);

  // --- adaLN params ---
  k_adaln<<<PDIM, 256, 0, stream>>>(c, aw, ab, params);

  // --- MSA branch ---
  k_lnmodq<0><<<NTOK, 256, 0, stream>>>(x, nullptr, params, 0, D_, 0, nullptr, xqa, s1);
  k_gemm<0><<<dim3(8,64), 256, 0, stream>>>(xqa, meta.q[0], bufI, s1, wdeq+0, D_, D_, nullptr, nullptr);
  k_gemm<0><<<dim3(8,64), 256, 0, stream>>>(xqa, meta.q[1], bufF, s1, wdeq+1, D_, D_, nullptr, nullptr);
  k_gemm<0><<<dim3(8,64), 256, 0, stream>>>(xqa, meta.q[2], bufG, s1, wdeq+2, D_, D_, nullptr, nullptr);
  k_ewif<<<2048, 256, 0, stream>>>(bufI, bufF, NTOK*D_/4);
  k_scanA<<<512, 256, 0, stream>>>(bufF, bufI, scAc, scHc);
  k_scanB<<<16,  256, 0, stream>>>(scAc, scHc, scH0);
  k_scanC<<<512, 256, 0, stream>>>(bufF, bufI, scH0, bufH);
  k_ogateq<<<NTOK, 256, 0, stream>>>(bufH, bufG, gnw, xqa, s2);
  k_gemm<0><<<dim3(8,64), 256, 0, stream>>>(xqa, meta.q[3], bufAT, s2, wdeq+3, D_, D_, nullptr, nullptr);

  // --- residual + MLP branch ---
  k_lnmodq<1><<<NTOK, 256, 0, stream>>>(x, bufAT, params, 3*D_, 4*D_, 2*D_, x2, xqa, s3);
  k_gemm_gate<<<dim3(32,64), 256, 0, stream>>>(xqa, meta.q[4], hsw, s3, wdeq+4, D_);
  k_mlpq<<<NTOK, 256, 0, stream>>>(hsw, xqh, sh);
  k_gemm<1><<<dim3(8,64), 256, 0, stream>>>(xqh, meta.q[5], out, sh, wdeq+5, D_, HID, x2, params);
}

// Round 2
// 603.945 us; speedup vs baseline: 1.1649x; 1.1649x over previous
//
#include <hip/hip_runtime.h>
#include <cstdint>
#include <cstddef>

#define B_   4
#define T_   2048
#define D_   1024
#define NTOK (B_*T_)          // 8192 tokens
#define HID  4096             // MLP_HIDDEN
#define PDIM (6*D_)           // 6144

typedef int v4i __attribute__((ext_vector_type(4)));
typedef __attribute__((ext_vector_type(8))) unsigned short ushort8v;

__device__ __forceinline__ float sigf(float x){ return 1.0f/(1.0f+expf(-x)); }

__device__ __forceinline__ float b2f(uint16_t u){ union{uint32_t i; float f;} x; x.i = ((uint32_t)u)<<16; return x.f; }
__device__ __forceinline__ uint16_t f2b(float f){
  union{float f; uint32_t i;} x; x.f=f;
  uint32_t r = x.i + 0x7fff + ((x.i>>16)&1);   // RNE
  return (uint16_t)(r>>16);
}

// swizzle: permute 16B sub-blocks within each 64B group of a row by XOR with (row>>1)&3.
// wi = 4-byte word index within the row. Producers write at swz_word(wi,row); the GEMM
// ds_read applies the same XOR. global_load_lds stays linear (both-sides rule, m104/m231).
__device__ __forceinline__ int swz_word(int wi, int row){
  return (wi & ~15) | ((((wi>>2)&3) ^ ((row>>1)&3))<<2) | (wi&3);
}

// ---------- block reductions (256 threads) ----------
__device__ __forceinline__ float bsum256(float v, float* sm, int tid){
#pragma unroll
  for (int o=32;o;o>>=1) v += __shfl_down(v,o);
  if ((tid&63)==0) sm[tid>>6]=v;
  __syncthreads();
  float r = sm[0]+sm[1]+sm[2]+sm[3];
  __syncthreads();
  return r;
}
__device__ __forceinline__ void bsummax256(float& s, float& m, float* sm, int tid){
#pragma unroll
  for (int o=32;o;o>>=1){ s += __shfl_down(s,o); m = fmaxf(m,__shfl_down(m,o)); }
  if ((tid&63)==0){ sm[tid>>6]=s; sm[4+(tid>>6)]=m; }
  __syncthreads();
  s = sm[0]+sm[1]+sm[2]+sm[3];
  m = fmaxf(fmaxf(sm[4],sm[5]),fmaxf(sm[6],sm[7]));
  __syncthreads();
}

__device__ __forceinline__ uint32_t pack4(float a, float b, float c, float d, float k){
  int q0=(int)rintf(a*k); q0 = q0<-128?-128:(q0>127?127:q0);
  int q1=(int)rintf(b*k); q1 = q1<-128?-128:(q1>127?127:q1);
  int q2=(int)rintf(c*k); q2 = q2<-128?-128:(q2>127?127:q2);
  int q3=(int)rintf(d*k); q3 = q3<-128?-128:(q3>127?127:q3);
  return (uint32_t)(q0&255) | ((uint32_t)(q1&255)<<8) | ((uint32_t)(q2&255)<<16) | ((uint32_t)(q3&255)<<24);
}

// ---------- weight ternarization ----------
struct WMeta {
  const float* w[6];
  int8_t* q[6];
  int n[6];
  int kws[6];   // log2(words per row) = log2(K/4)
};

__global__ __launch_bounds__(256) void k_wabs(WMeta meta, float* __restrict__ partial){
  int mat = blockIdx.y;
  const float* w = meta.w[mat];
  int n = meta.n[mat];
  int tid = threadIdx.x;
  float s = 0.f;
  for (int i = blockIdx.x*256 + tid; i < n; i += 256*gridDim.x) s += fabsf(w[i]);
  __shared__ float sm[4];
#pragma unroll
  for (int o=32;o;o>>=1) s += __shfl_down(s,o);
  if ((tid&63)==0) sm[tid>>6]=s;
  __syncthreads();
  if (tid==0) partial[mat*256 + blockIdx.x] = sm[0]+sm[1]+sm[2]+sm[3];
}

__global__ __launch_bounds__(256) void k_wfin(WMeta meta, const float* __restrict__ partial, float* __restrict__ wdeq){
  int mat = blockIdx.x;
  int tid = threadIdx.x;
  float s = partial[mat*256 + tid];
  __shared__ float sm[4];
#pragma unroll
  for (int o=32;o;o>>=1) s += __shfl_down(s,o);
  if ((tid&63)==0) sm[tid>>6]=s;
  __syncthreads();
  if (tid==0){
    float mean = (sm[0]+sm[1]+sm[2]+sm[3]) / (float)meta.n[mat];
    wdeq[mat] = fmaxf(mean, 1e-5f);   // = 1/ws (dequant scale)
  }
}

// vectorized + swizzled ternary quant (one uint32 = 4 weights per thread)
__global__ __launch_bounds__(256) void k_wquant(WMeta meta, const float* __restrict__ wdeq){
  int mat = blockIdx.y;
  const float* w = meta.w[mat];
  uint32_t* q = (uint32_t*)meta.q[mat];
  int nw = meta.n[mat]>>2;
  int kws = meta.kws[mat];
  int kwmask = (1<<kws)-1;
  float ws = 1.0f / wdeq[mat];
  for (int i = blockIdx.x*256 + threadIdx.x; i < nw; i += 256*gridDim.x){
    float4 v = ((const float4*)w)[i];
    int q0=(int)rintf(v.x*ws); q0=q0<-1?-1:(q0>1?1:q0);
    int q1=(int)rintf(v.y*ws); q1=q1<-1?-1:(q1>1?1:q1);
    int q2=(int)rintf(v.z*ws); q2=q2<-1?-1:(q2>1?1:q2);
    int q3=(int)rintf(v.w*ws); q3=q3<-1?-1:(q3>1?1:q3);
    uint32_t packed = (uint32_t)(q0&255) | ((uint32_t)(q1&255)<<8) | ((uint32_t)(q2&255)<<16) | ((uint32_t)(q3&255)<<24);
    int row = i >> kws, wi = i & kwmask;
    q[((size_t)row<<kws) + swz_word(wi,row)] = packed;
  }
}

// ---------- adaLN: params = silu(c) @ adaln_w.T + adaln_b ----------
__global__ __launch_bounds__(256) void k_adaln(const float* __restrict__ c, const float* __restrict__ w,
                                               const float* __restrict__ bias, float* __restrict__ params){
  int wv = threadIdx.x>>6, lane = threadIdx.x&63;
  int oidx = blockIdx.x*4 + wv;           // 0..24575
  int b = oidx / PDIM, j = oidx % PDIM;
  const float* cr = c + b*D_;
  const float* wr = w + (size_t)j*D_;
  float s = 0.f;
  for (int k = lane; k < D_; k += 64){
    float cv = cr[k];
    s += (cv*sigf(cv)) * wr[k];
  }
#pragma unroll
  for (int o=32;o;o>>=1) s += __shfl_down(s,o);
  if (lane==0) params[oidx] = s + bias[j];
}

// ---------- [residual +] LayerNorm + modulate + rmsnorm + int8 quant (one token/block) ----------
template<int RES>
__global__ __launch_bounds__(256) void k_lnmodq(const float* __restrict__ xin,
    const float* __restrict__ addv, const float* __restrict__ params,
    int shift_off, int scale_off, int gate_off,
    float* __restrict__ x2out, int8_t* __restrict__ xq, float* __restrict__ dq){
  int tok = blockIdx.x;
  int b = tok >> 11;
  int tid = threadIdx.x;
  __shared__ float sm[8];
  const float* pb = params + (size_t)b*PDIM;
  float4 v = ((const float4*)(xin + (size_t)tok*D_))[tid];
  if (RES){
    float4 a = ((const float4*)(addv + (size_t)tok*D_))[tid];
    float4 g = ((const float4*)(pb + gate_off))[tid];
    v.x = fmaf(g.x,a.x,v.x); v.y = fmaf(g.y,a.y,v.y);
    v.z = fmaf(g.z,a.z,v.z); v.w = fmaf(g.w,a.w,v.w);
    ((float4*)(x2out + (size_t)tok*D_))[tid] = v;
  }
  float mu = bsum256(v.x+v.y+v.z+v.w, sm, tid) * (1.0f/D_);
  float t0=v.x-mu, t1=v.y-mu, t2=v.z-mu, t3=v.w-mu;
  float var = bsum256(t0*t0+t1*t1+t2*t2+t3*t3, sm, tid) * (1.0f/D_);
  float rstd = rsqrtf(var + 1e-6f);
  float4 sc = ((const float4*)(pb + scale_off))[tid];
  float4 sh = ((const float4*)(pb + shift_off))[tid];
  float y0 = fmaf(t0*rstd, 1.0f+sc.x, sh.x);
  float y1 = fmaf(t1*rstd, 1.0f+sc.y, sh.y);
  float y2 = fmaf(t2*rstd, 1.0f+sc.z, sh.z);
  float y3 = fmaf(t3*rstd, 1.0f+sc.w, sh.w);
  float ssq = y0*y0+y1*y1+y2*y2+y3*y3;
  float mx = fmaxf(fmaxf(fabsf(y0),fabsf(y1)),fmaxf(fabsf(y2),fabsf(y3)));
  bsummax256(ssq, mx, sm, tid);
  float rms = rsqrtf(ssq*(1.0f/D_) + 1e-8f);
  float a = fmaxf(mx*rms, 1e-5f);
  float s = 127.0f/a;
  float k = rms*s;
  ((uint32_t*)(xq + (size_t)tok*D_))[swz_word(tid,tok)] = pack4(y0,y1,y2,y3,k);
  if (tid==0) dq[tok] = 1.0f/s;
}

// ================= GEMM kernels: 2-phase dbuf + swizzled ds_read =================
// Out[M,N] = (Aq[M,K] . Bq[N,K]^T) * adq[row] * wdq
// MODE 0: f32 out; MODE 1: bf16 out; MODE 2: f32 out = resid + gate_mlp*val (down-proj)
template<int MODE>
__global__ __launch_bounds__(256) void k_gemm(const int8_t* __restrict__ Aq, const int8_t* __restrict__ Bq,
    void* __restrict__ Outv, const float* __restrict__ adq, const float* __restrict__ wdq_ptr,
    int N, int K, const float* __restrict__ resid, const float* __restrict__ params){
  __shared__ int8_t lA[2][8192], lB[2][8192];
  const int tid = threadIdx.x;
  const int wave = tid>>6, lane = tid&63;
  const int row0 = blockIdx.y<<7, col0 = blockIdx.x<<7;
  const int wm = (wave>>1)<<6, wn = (wave&1)<<6;
  v4i acc[4][4];
#pragma unroll
  for (int m=0;m<4;m++)
#pragma unroll
    for (int n=0;n<4;n++) acc[m][n] = (v4i){0,0,0,0};
  const int rA = lane&15, kg = lane>>4;
  const int axor = (rA>>1)&3;
  const int r_st = tid>>2, cb_st = (tid&3)<<4;

  auto STAGE = [&](int buf, int k0){
#pragma unroll
    for (int p=0;p<2;p++){
      int r = p*64 + r_st;
      __builtin_amdgcn_global_load_lds((const __attribute__((address_space(1))) void*)(Aq + (size_t)(row0+r)*K + k0 + cb_st),
        (__attribute__((address_space(3))) void*)(&lA[buf][p*4096 + wave*1024]), 16, 0, 0);
      __builtin_amdgcn_global_load_lds((const __attribute__((address_space(1))) void*)(Bq + (size_t)(col0+r)*K + k0 + cb_st),
        (__attribute__((address_space(3))) void*)(&lB[buf][p*4096 + wave*1024]), 16, 0, 0);
    }
  };
  auto COMPUTE = [&](int buf){
    const v4i* la4 = (const v4i*)lA[buf];
    const v4i* lb4 = (const v4i*)lB[buf];
    v4i af[4], bf[4];
#pragma unroll
    for (int m=0;m<4;m++){ int r = wm + m*16 + rA; af[m] = la4[(r<<2) + (kg^axor)]; }
#pragma unroll
    for (int n=0;n<4;n++){ int r = wn + n*16 + rA; bf[n] = lb4[(r<<2) + (kg^axor)]; }
#pragma unroll
    for (int m=0;m<4;m++)
#pragma unroll
      for (int n=0;n<4;n++)
        acc[m][n] = __builtin_amdgcn_mfma_i32_16x16x64_i8(af[m], bf[n], acc[m][n], 0, 0, 0);
  };

  STAGE(0, 0);
  __syncthreads();
  int cur = 0;
  for (int k0=64; k0<K; k0+=64){
    STAGE(cur^1, k0);
    COMPUTE(cur);
    __syncthreads();
    cur ^= 1;
  }
  COMPUTE(cur);

  float wdq = wdq_ptr[0];
  int rr = (lane>>4)<<2, cl = lane&15;
#pragma unroll
  for (int m=0;m<4;m++){
#pragma unroll
    for (int r=0;r<4;r++){
      int row = row0 + wm + m*16 + rr + r;
      float scale = adq[row]*wdq;
#pragma unroll
      for (int n=0;n<4;n++){
        int col = col0 + wn + n*16 + cl;
        size_t oi = (size_t)row*N + col;
        float val = (float)acc[m][n][r]*scale;
        if (MODE==0) ((float*)Outv)[oi] = val;
        if (MODE==1) ((uint16_t*)Outv)[oi] = f2b(val);
        if (MODE==2){
          int bb = row>>11;
          ((float*)Outv)[oi] = resid[oi] + params[(size_t)bb*PDIM + 5*D_ + col]*val;
        }
      }
    }
  }
}

// 2-B-matrix GEMM. MODE 0 (IF): out0 = bf16 silu(i)*(1-sigmoid(f)), out1 = bf16 sigmoid(f)
// MODE 1 (GATE): Bq1 implied = Bq0 + HID*K, out0 = bf16 silu(g)*y
template<int MODE>
__global__ __launch_bounds__(256) void k_gemm2(const int8_t* __restrict__ Aq, const int8_t* __restrict__ Bq0,
    const int8_t* __restrict__ Bq1, uint16_t* __restrict__ out0, uint16_t* __restrict__ out1,
    const float* __restrict__ adq, const float* __restrict__ wdq_ptr, int i0, int i1, int N, int K){
  __shared__ int8_t lA[2][8192], lB0[2][8192], lB1[2][8192];
  const int tid = threadIdx.x;
  const int wave = tid>>6, lane = tid&63;
  const int row0 = blockIdx.y<<7, col0 = blockIdx.x<<7;
  const int wm = (wave>>1)<<6, wn = (wave&1)<<6;
  v4i acc0[4][4], acc1[4][4];
#pragma unroll
  for (int m=0;m<4;m++)
#pragma unroll
    for (int n=0;n<4;n++){ acc0[m][n] = (v4i){0,0,0,0}; acc1[m][n] = (v4i){0,0,0,0}; }
  const int rA = lane&15, kg = lane>>4;
  const int axor = (rA>>1)&3;
  const int r_st = tid>>2, cb_st = (tid&3)<<4;

  auto STAGE = [&](int buf, int k0){
#pragma unroll
    for (int p=0;p<2;p++){
      int r = p*64 + r_st;
      __builtin_amdgcn_global_load_lds((const __attribute__((address_space(1))) void*)(Aq  + (size_t)(row0+r)*K + k0 + cb_st),
        (__attribute__((address_space(3))) void*)(&lA[buf][p*4096 + wave*1024]), 16, 0, 0);
      __builtin_amdgcn_global_load_lds((const __attribute__((address_space(1))) void*)(Bq0 + (size_t)(col0+r)*K + k0 + cb_st),
        (__attribute__((address_space(3))) void*)(&lB0[buf][p*4096 + wave*1024]), 16, 0, 0);
      __builtin_amdgcn_global_load_lds((const __attribute__((address_space(1))) void*)(Bq1 + (size_t)(col0+r)*K + k0 + cb_st),
        (__attribute__((address_space(3))) void*)(&lB1[buf][p*4096 + wave*1024]), 16, 0, 0);
    }
  };
  auto COMPUTE = [&](int buf){
    const v4i* la4 = (const v4i*)lA[buf];
    const v4i* lb4 = (const v4i*)lB0[buf];
    const v4i* lc4 = (const v4i*)lB1[buf];
    v4i af[4], bf[4], cf[4];
#pragma unroll
    for (int m=0;m<4;m++){ int r = wm + m*16 + rA; af[m] = la4[(r<<2) + (kg^axor)]; }
#pragma unroll
    for (int n=0;n<4;n++){ int r = wn + n*16 + rA; bf[n] = lb4[(r<<2) + (kg^axor)]; cf[n] = lc4[(r<<2) + (kg^axor)]; }
#pragma unroll
    for (int m=0;m<4;m++)
#pragma unroll
      for (int n=0;n<4;n++){
        acc0[m][n] = __builtin_amdgcn_mfma_i32_16x16x64_i8(af[m], bf[n], acc0[m][n], 0, 0, 0);
        acc1[m][n] = __builtin_amdgcn_mfma_i32_16x16x64_i8(af[m], cf[n], acc1[m][n], 0, 0, 0);
      }
  };

  STAGE(0, 0);
  __syncthreads();
  int cur = 0;
  for (int k0=64; k0<K; k0+=64){
    STAGE(cur^1, k0);
    COMPUTE(cur);
    __syncthreads();
    cur ^= 1;
  }
  COMPUTE(cur);

  float wdq0 = wdq_ptr[i0], wdq1 = wdq_ptr[i1];
  int rr = (lane>>4)<<2, cl = lane&15;
#pragma unroll
  for (int m=0;m<4;m++){
#pragma unroll
    for (int r=0;r<4;r++){
      int row = row0 + wm + m*16 + rr + r;
      float scale = adq[row];
#pragma unroll
      for (int n=0;n<4;n++){
        int col = col0 + wn + n*16 + cl;
        size_t oi = (size_t)row*N + col;
        float v0 = (float)acc0[m][n][r]*scale*wdq0;
        float v1 = (float)acc1[m][n][r]*scale*wdq1;
        if (MODE==0){ // IF: i' and f'
          float fs = sigf(v1);
          out0[oi] = f2b(v0*sigf(v0)*(1.0f-fs));
          out1[oi] = f2b(fs);
        } else {      // GATE: silu(g)*y
          out0[oi] = f2b(v0*sigf(v0)*v1);
        }
      }
    }
  }
}

// ---------- chunked linear-recurrence scan: h_t = f_t*h_{t-1} + i_t (bf16 in, f32 out) ----------
__global__ __launch_bounds__(256) void k_scanA(const uint16_t* __restrict__ f, const uint16_t* __restrict__ ii,
                                               float* __restrict__ Ac, float* __restrict__ Hc){
  int idx = blockIdx.x*256 + threadIdx.x;   // < 131072
  int ch = idx >> 12;
  int c  = idx & 4095;
  int b = c >> 10, d = c & 1023;
  size_t base = ((size_t)(b*T_ + ch*64))*D_ + d;
  float a = 1.f, h = 0.f;
  for (int t=0;t<64;t++){
    float ft = b2f(f[base + (size_t)t*D_]);
    float it = b2f(ii[base + (size_t)t*D_]);
    a *= ft;
    h = ft*h + it;
  }
  Ac[ch*4096 + c] = a;
  Hc[ch*4096 + c] = h;
}
__global__ __launch_bounds__(256) void k_scanB(const float* __restrict__ Ac, const float* __restrict__ Hc,
                                               float* __restrict__ H0){
  int c = blockIdx.x*256 + threadIdx.x;     // 4096
  float h = 0.f;
  for (int ch=0; ch<32; ch++){
    H0[ch*4096 + c] = h;
    h = Ac[ch*4096 + c]*h + Hc[ch*4096 + c];
  }
}
__global__ __launch_bounds__(256) void k_scanC(const uint16_t* __restrict__ f, const uint16_t* __restrict__ ii,
                                               const float* __restrict__ H0, float* __restrict__ hout){
  int idx = blockIdx.x*256 + threadIdx.x;
  int ch = idx >> 12;
  int c  = idx & 4095;
  int b = c >> 10, d = c & 1023;
  size_t base = ((size_t)(b*T_ + ch*64))*D_ + d;
  float h = H0[ch*4096 + c];
  for (int t=0;t<64;t++){
    float ft = b2f(f[base + (size_t)t*D_]);
    float it = b2f(ii[base + (size_t)t*D_]);
    h = ft*h + it;
    hout[base + (size_t)t*D_] = h;
  }
}

// ---------- o = rmsnorm_head(h)*gnorm_w*(g*sig(g)); then row rmsnorm + quant ----------
__global__ __launch_bounds__(256) void k_ogateq(const float* __restrict__ h, const uint16_t* __restrict__ g,
    const float* __restrict__ gnw, int8_t* __restrict__ xq, float* __restrict__ dq){
  int tok = blockIdx.x, tid = threadIdx.x;
  __shared__ float sm[8];
  float4 hv = ((const float4*)(h + (size_t)tok*D_))[tid];
  float ss = hv.x*hv.x + hv.y*hv.y + hv.z*hv.z + hv.w*hv.w;
  ss += __shfl_xor(ss,1); ss += __shfl_xor(ss,2); ss += __shfl_xor(ss,4); ss += __shfl_xor(ss,8);
  float rh = rsqrtf(ss*(1.0f/64.0f) + 1e-5f);
  ushort4 gv = ((const ushort4*)(g + (size_t)tok*D_))[tid];
  float g0=b2f(gv.x), g1=b2f(gv.y), g2=b2f(gv.z), g3=b2f(gv.w);
  int hd = (tid*4)&63;
  float o0 = hv.x*rh*gnw[hd+0]*(g0*sigf(g0));
  float o1 = hv.y*rh*gnw[hd+1]*(g1*sigf(g1));
  float o2 = hv.z*rh*gnw[hd+2]*(g2*sigf(g2));
  float o3 = hv.w*rh*gnw[hd+3]*(g3*sigf(g3));
  float ssq = o0*o0+o1*o1+o2*o2+o3*o3;
  float mx = fmaxf(fmaxf(fabsf(o0),fabsf(o1)),fmaxf(fabsf(o2),fabsf(o3)));
  bsummax256(ssq, mx, sm, tid);
  float rms = rsqrtf(ssq*(1.0f/D_) + 1e-8f);
  float a = fmaxf(mx*rms, 1e-5f);
  float s = 127.0f/a;
  float k = rms*s;
  ((uint32_t*)(xq + (size_t)tok*D_))[swz_word(tid,tok)] = pack4(o0,o1,o2,o3,k);
  if (tid==0) dq[tok] = 1.0f/s;
}

// ---------- quantize swiglu output (4096-wide bf16 rows) ----------
__global__ __launch_bounds__(256) void k_mlpq(const uint16_t* __restrict__ hsw, int8_t* __restrict__ xq,
                                              float* __restrict__ dq){
  int tok = blockIdx.x, tid = threadIdx.x;
  __shared__ float sm[8];
  const ushort8v* r8 = (const ushort8v*)(hsw + (size_t)tok*HID);
  float v[2][8];
  float ssq = 0.f, mx = 0.f;
#pragma unroll
  for (int j=0;j<2;j++){
    ushort8v u = r8[tid + j*256];
#pragma unroll
    for (int e=0;e<8;e++){
      float fv = b2f(u[e]);
      v[j][e] = fv;
      ssq += fv*fv;
      mx = fmaxf(mx, fabsf(fv));
    }
  }
  bsummax256(ssq, mx, sm, tid);
  float rms = rsqrtf(ssq*(1.0f/HID) + 1e-8f);
  float a = fmaxf(mx*rms, 1e-5f);
  float s = 127.0f/a;
  float k = rms*s;
  uint32_t* qw = (uint32_t*)(xq + (size_t)tok*HID);
#pragma unroll
  for (int j=0;j<2;j++){
    int u = tid + j*256;     // ushort8 unit -> words 2u, 2u+1
    qw[swz_word(2*u,   tok)] = pack4(v[j][0],v[j][1],v[j][2],v[j][3],k);
    qw[swz_word(2*u+1, tok)] = pack4(v[j][4],v[j][5],v[j][6],v[j][7],k);
  }
  if (tid==0) dq[tok] = 1.0f/s;
}

// =====================================================================

extern "C" void kernel_launch(void* const* d_in, const int* in_sizes, int n_in,
                              void* d_out, int out_size, void* d_ws, size_t ws_size,
                              hipStream_t stream){
  (void)in_sizes; (void)n_in; (void)out_size; (void)ws_size;
  const float* x     = (const float*)d_in[0];
  const float* c     = (const float*)d_in[1];
  const float* aw    = (const float*)d_in[2];
  const float* ab    = (const float*)d_in[3];
  const float* wi    = (const float*)d_in[4];
  const float* wf    = (const float*)d_in[5];
  const float* wg    = (const float*)d_in[6];
  const float* gnw   = (const float*)d_in[7];
  const float* wo    = (const float*)d_in[8];
  const float* wgate = (const float*)d_in[9];
  const float* wdown = (const float*)d_in[10];
  float* out = (float*)d_out;

  char* ws = (char*)d_ws;
  size_t off = 0;
  auto alloc = [&](size_t b){ size_t r = off; off += (b + 255) & ~(size_t)255; return r; };

  size_t oWQ[6];
  oWQ[0] = alloc(1024*1024);            // wi q
  oWQ[1] = alloc(1024*1024);            // wf q
  oWQ[2] = alloc(1024*1024);            // wg q
  oWQ[3] = alloc(1024*1024);            // wo q
  oWQ[4] = alloc((size_t)8192*1024);    // gate q
  oWQ[5] = alloc((size_t)1024*4096);    // down q
  size_t oWDEQ = alloc(6*4);
  size_t oPART = alloc(6*256*4);
  size_t oPAR  = alloc((size_t)4*PDIM*4);
  size_t oS1 = alloc(NTOK*4), oS2 = alloc(NTOK*4), oS3 = alloc(NTOK*4), oSH = alloc(NTOK*4);
  size_t oXQA  = alloc((size_t)NTOK*D_);                 // 8MB int8 (reused 3x)
  // pool: [bi bf16 16.78M][bf bf16 16.78M][bg bf16 16.78M][h f32 33.55M][AT f32 33.55M]
  // hsw (bf16 [8192][4096] = 67.1M) overlays bi..h; xqh (i8 33.55M) overlays AT
  size_t oPOOL = alloc((size_t)3*NTOK*D_*2 + (size_t)2*NTOK*D_*4);
  size_t oX2   = alloc((size_t)NTOK*D_*4);
  size_t oSA = alloc((size_t)32*4096*4), oSHc = alloc((size_t)32*4096*4), oSH0 = alloc((size_t)32*4096*4);

  float*  params = (float*)(ws+oPAR);
  float*  wdeq   = (float*)(ws+oWDEQ);
  float*  part   = (float*)(ws+oPART);
  float*  s1 = (float*)(ws+oS1); float* s2 = (float*)(ws+oS2);
  float*  s3 = (float*)(ws+oS3); float* sh = (float*)(ws+oSH);
  int8_t* xqa = (int8_t*)(ws+oXQA);
  uint16_t* bI  = (uint16_t*)(ws+oPOOL);                        // i' bf16
  uint16_t* bF  = bI + (size_t)NTOK*D_;                          // f' bf16
  uint16_t* bG  = bF + (size_t)NTOK*D_;                          // g  bf16
  float*    bufH  = (float*)(bG + (size_t)NTOK*D_);              // h f32
  float*    bufAT = bufH + (size_t)NTOK*D_;                      // attn out f32
  uint16_t* hsw   = bI;                                          // swiglu bf16, overlays bi..h
  int8_t*   xqh   = (int8_t*)bufAT;                              // i8, overlays AT
  float*  x2    = (float*)(ws+oX2);
  float*  scAc = (float*)(ws+oSA); float* scHc = (float*)(ws+oSHc); float* scH0 = (float*)(ws+oSH0);

  WMeta meta;
  meta.w[0]=wi; meta.w[1]=wf; meta.w[2]=wg; meta.w[3]=wo; meta.w[4]=wgate; meta.w[5]=wdown;
  for (int m=0;m<6;m++) meta.q[m] = (int8_t*)(ws+oWQ[m]);
  meta.n[0]=meta.n[1]=meta.n[2]=meta.n[3]=1024*1024; meta.n[4]=8192*1024; meta.n[5]=1024*4096;
  meta.kws[0]=meta.kws[1]=meta.kws[2]=meta.kws[3]=meta.kws[4]=8; meta.kws[5]=10;

  // --- weight ternarization ---
  k_wabs  <<<dim3(256,6), 256, 0, stream>>>(meta, part);
  k_wfin  <<<6,           256, 0, stream>>>(meta, part, wdeq);
  k_wquant<<<dim3(1024,6),256, 0, stream>>>(meta, wdeq);

  // --- adaLN params ---
  k_adaln<<<PDIM, 256, 0, stream>>>(c, aw, ab, params);

  // --- MSA branch ---
  k_lnmodq<0><<<NTOK, 256, 0, stream>>>(x, nullptr, params, 0, D_, 0, nullptr, xqa, s1);
  // fused wi+wf GEMM -> i' = silu(i)*(1-f'), f' = sigmoid(f)   (bf16)
  k_gemm2<0><<<dim3(8,64), 256, 0, stream>>>(xqa, meta.q[0], meta.q[1], bI, bF, s1, wdeq, 0, 1, D_, D_);
  // wg GEMM -> g (bf16)
  k_gemm<1><<<dim3(8,64), 256, 0, stream>>>(xqa, meta.q[2], bG, s1, wdeq+2, D_, D_, nullptr, nullptr);
  k_scanA<<<512, 256, 0, stream>>>(bF, bI, scAc, scHc);
  k_scanB<<<16,  256, 0, stream>>>(scAc, scHc, scH0);
  k_scanC<<<512, 256, 0, stream>>>(bF, bI, scH0, bufH);
  k_ogateq<<<NTOK, 256, 0, stream>>>(bufH, bG, gnw, xqa, s2);
  k_gemm<0><<<dim3(8,64), 256, 0, stream>>>(xqa, meta.q[3], bufAT, s2, wdeq+3, D_, D_, nullptr, nullptr);

  // --- residual + MLP branch ---
  k_lnmodq<1><<<NTOK, 256, 0, stream>>>(x, bufAT, params, 3*D_, 4*D_, 2*D_, x2, xqa, s3);
  // gate-proj: both halves, writes bf16 silu(gate)*y [8192][4096]
  k_gemm2<1><<<dim3(32,64), 256, 0, stream>>>(xqa, meta.q[4], meta.q[4] + (size_t)HID*1024, hsw, nullptr, s3, wdeq+4, 0, 0, HID, D_);
  k_mlpq<<<NTOK, 256, 0, stream>>>(hsw, xqh, sh);
  k_gemm<2><<<dim3(8,64), 256, 0, stream>>>(xqh, meta.q[5], out, sh, wdeq+5, D_, HID, x2, params);
}